// Round 6
// baseline (536.414 us; speedup 1.0000x reference)
//
#include <hip/hip_runtime.h>
#include <hip/hip_cooperative_groups.h>
#include <math.h>

namespace cg = cooperative_groups;

// ---------------------------------------------------------------------------
// MS-SSIM 3D (window 11, sigma 1.5, 5 levels) for (2,1,192,192,192) fp32 pairs.
//
// R6: ONE cooperative dispatch. Phase 0: zero ws scalars. grid.sync.
// Phase 1: fused pyramid (all pooled levels + per-level min/max of img1).
// grid.sync. Phase 2: ssim work items (all 5 levels) via atomic work-stealing
// (items ordered large->small); last finished item computes the final scalar.
//
// ws float layout:
//   [0..4]   ssim_sum[level]      (float atomics)
//   [5..9]   cs_sum[level]        (float atomics)
//   [10..14] min_enc[level]       (sortable-uint atomicMin)
//   [15..19] max_enc[level]       (sortable-uint atomicMax)
//   [20]     done counter (uint)  [21] work-steal counter (uint)
//   [32.. ]  pyramid images (levels 1..4, img1 then img2 per level)
// ---------------------------------------------------------------------------

__device__ __forceinline__ unsigned enc_f(float f) {
    unsigned u = __float_as_uint(f);
    return (u & 0x80000000u) ? ~u : (u | 0x80000000u);
}
__device__ __forceinline__ float dec_f(unsigned e) {
    unsigned u = (e & 0x80000000u) ? (e ^ 0x80000000u) : ~e;
    return __uint_as_float(u);
}

#define TSX 16
#define TSY 32
#define EXR 42            // ext rows (32+10)
#define EXC 26            // ext cols (16+10)
#define SPS 30            // S row stride in float2
#define NPIX (EXR * EXC)  // 1092
#define TPS 17            // TX row stride (float4 / float units)

struct MegaParams {
    // pyramid
    const float* src[2];   // img1, img2
    float* dst[2][4];      // [img][level-1]
    // ssim
    const float* A[5];
    const float* B[5];
    int D[5], O[5], zc[5], nTx[5], nTy[5];
    int blk0[6];           // cumulative item offsets, level order 0..4
    float* out;
    double cnt[5];
};

// LDS overlay (ssim needs 26408 B, pyramid 18720 B)
#define LDS_BYTES 26912

__launch_bounds__(256, 2)
__attribute__((amdgpu_waves_per_eu(2, 2)))
__global__ void mega_kernel(MegaParams P, float* wsf) {
    __shared__ __align__(16) char LB[LDS_BYTES];
    __shared__ int sItem;
    unsigned* wsu = (unsigned*)wsf;
    const int tid = threadIdx.x;

    // ================= phase 0: init ws scalars =================
    if (blockIdx.x == 0) {
        if (tid < 10)       wsf[tid] = 0.0f;
        else if (tid < 15)  wsu[tid] = 0xFFFFFFFFu;  // min slots
        else if (tid < 20)  wsu[tid] = 0u;           // max slots
        else if (tid < 22)  wsu[tid] = 0u;           // done + steal counters
    }
    cg::this_grid().sync();

    // ================= phase 1: pyramid =================
    {
        float* L1  = (float*)LB;            // 16^3 = 16384 B
        float* L2s = (float*)(LB + 16384);  // 8^3
        float* L3s = (float*)(LB + 18432);  // 4^3
        float* smn = (float*)(LB + 18688);
        float* smx = (float*)(LB + 18704);

        for (int p = blockIdx.x; p < 864; p += gridDim.x) {
            int blk = p;
            int r = blk % 216; blk /= 216;
            int batch = blk & 1;
            int im = blk >> 1;
            const int rx = r % 6, ry = (r / 6) % 6, rz = r / 36;

            const long N0 = 192L * 192 * 192;
            const float* src = P.src[im] + (long)batch * N0;
            float* d1 = P.dst[im][0] + (long)batch * 96 * 96 * 96;
            float* d2 = P.dst[im][1] + (long)batch * 48 * 48 * 48;
            float* d3 = P.dst[im][2] + (long)batch * 24 * 24 * 24;
            float* d4 = P.dst[im][3] + (long)batch * 12 * 12 * 12;

            const int tx = tid & 15, ty = tid >> 4;
            float mnv[5], mxv[5];
#pragma unroll
            for (int l = 0; l < 5; l++) { mnv[l] = INFINITY; mxv[l] = -INFINITY; }

            const long D = 192, D2 = 192L * 192;
            const int gx = 2 * (rx * 16 + tx);
            const int gy = 2 * (ry * 16 + ty);
#pragma unroll 4
            for (int z = 0; z < 16; z++) {
                const int gz = 2 * (rz * 16 + z);
                long base = (long)gz * D2 + (long)gy * D + gx;
                float2 a00 = *(const float2*)(src + base);
                float2 a01 = *(const float2*)(src + base + D);
                float2 a10 = *(const float2*)(src + base + D2);
                float2 a11 = *(const float2*)(src + base + D2 + D);
                float lo = fminf(fminf(fminf(a00.x, a00.y), fminf(a01.x, a01.y)),
                                 fminf(fminf(a10.x, a10.y), fminf(a11.x, a11.y)));
                float hi = fmaxf(fmaxf(fmaxf(a00.x, a00.y), fmaxf(a01.x, a01.y)),
                                 fmaxf(fmaxf(a10.x, a10.y), fmaxf(a11.x, a11.y)));
                mnv[0] = fminf(mnv[0], lo); mxv[0] = fmaxf(mxv[0], hi);
                float s = (a00.x + a00.y + a01.x + a01.y +
                           a10.x + a10.y + a11.x + a11.y) * 0.125f;
                mnv[1] = fminf(mnv[1], s); mxv[1] = fmaxf(mxv[1], s);
                d1[(long)(rz * 16 + z) * 96 * 96 + (ry * 16 + ty) * 96 + (rx * 16 + tx)] = s;
                L1[z * 256 + ty * 16 + tx] = s;
            }
            __syncthreads();

#pragma unroll
            for (int k = 0; k < 2; k++) {
                int o = tid + (k << 8);
                int x = o & 7, y = (o >> 3) & 7, z = o >> 6;
                float s = (L1[(2 * z) * 256 + (2 * y) * 16 + 2 * x] +
                           L1[(2 * z) * 256 + (2 * y) * 16 + 2 * x + 1] +
                           L1[(2 * z) * 256 + (2 * y + 1) * 16 + 2 * x] +
                           L1[(2 * z) * 256 + (2 * y + 1) * 16 + 2 * x + 1] +
                           L1[(2 * z + 1) * 256 + (2 * y) * 16 + 2 * x] +
                           L1[(2 * z + 1) * 256 + (2 * y) * 16 + 2 * x + 1] +
                           L1[(2 * z + 1) * 256 + (2 * y + 1) * 16 + 2 * x] +
                           L1[(2 * z + 1) * 256 + (2 * y + 1) * 16 + 2 * x + 1]) * 0.125f;
                mnv[2] = fminf(mnv[2], s); mxv[2] = fmaxf(mxv[2], s);
                d2[(long)(rz * 8 + z) * 48 * 48 + (ry * 8 + y) * 48 + (rx * 8 + x)] = s;
                L2s[o] = s;
            }
            __syncthreads();

            if (tid < 64) {
                int x = tid & 3, y = (tid >> 2) & 3, z = tid >> 4;
                float s = (L2s[(2 * z) * 64 + (2 * y) * 8 + 2 * x] +
                           L2s[(2 * z) * 64 + (2 * y) * 8 + 2 * x + 1] +
                           L2s[(2 * z) * 64 + (2 * y + 1) * 8 + 2 * x] +
                           L2s[(2 * z) * 64 + (2 * y + 1) * 8 + 2 * x + 1] +
                           L2s[(2 * z + 1) * 64 + (2 * y) * 8 + 2 * x] +
                           L2s[(2 * z + 1) * 64 + (2 * y) * 8 + 2 * x + 1] +
                           L2s[(2 * z + 1) * 64 + (2 * y + 1) * 8 + 2 * x] +
                           L2s[(2 * z + 1) * 64 + (2 * y + 1) * 8 + 2 * x + 1]) * 0.125f;
                mnv[3] = fminf(mnv[3], s); mxv[3] = fmaxf(mxv[3], s);
                d3[(long)(rz * 4 + z) * 24 * 24 + (ry * 4 + y) * 24 + (rx * 4 + x)] = s;
                L3s[tid] = s;
            }
            __syncthreads();

            if (tid < 8) {
                int x = tid & 1, y = (tid >> 1) & 1, z = tid >> 2;
                float s = (L3s[(2 * z) * 16 + (2 * y) * 4 + 2 * x] +
                           L3s[(2 * z) * 16 + (2 * y) * 4 + 2 * x + 1] +
                           L3s[(2 * z) * 16 + (2 * y + 1) * 4 + 2 * x] +
                           L3s[(2 * z) * 16 + (2 * y + 1) * 4 + 2 * x + 1] +
                           L3s[(2 * z + 1) * 16 + (2 * y) * 4 + 2 * x] +
                           L3s[(2 * z + 1) * 16 + (2 * y) * 4 + 2 * x + 1] +
                           L3s[(2 * z + 1) * 16 + (2 * y + 1) * 4 + 2 * x] +
                           L3s[(2 * z + 1) * 16 + (2 * y + 1) * 4 + 2 * x + 1]) * 0.125f;
                mnv[4] = fminf(mnv[4], s); mxv[4] = fmaxf(mxv[4], s);
                d4[(long)(rz * 2 + z) * 12 * 12 + (ry * 2 + y) * 12 + (rx * 2 + x)] = s;
            }

            const int lane = tid & 63, w = tid >> 6;
#pragma unroll
            for (int l = 0; l < 5; l++) {
                float mn = mnv[l], mx = mxv[l];
                for (int o = 32; o; o >>= 1) {
                    mn = fminf(mn, __shfl_down(mn, o));
                    mx = fmaxf(mx, __shfl_down(mx, o));
                }
                __syncthreads();
                if (lane == 0) { smn[w] = mn; smx[w] = mx; }
                __syncthreads();
                if (tid == 0 && im == 0) {
                    for (int i = 1; i < 4; i++) { mn = fminf(mn, smn[i]); mx = fmaxf(mx, smx[i]); }
                    atomicMin(&wsu[10 + l], enc_f(mn));
                    atomicMax(&wsu[15 + l], enc_f(mx));
                }
            }
            __syncthreads();
        }
    }
    cg::this_grid().sync();

    // ================= phase 2: ssim items (work stealing) =================
    float2* S   = (float2*)LB;              // 10080 B
    float4* TX4 = (float4*)(LB + 10080);    // 11424 B
    float*  TXe = (float*)(LB + 21504);     //  2856 B
    float2* RED = (float2*)(LB + 24360);    //  2048 B

    const int col = tid & 15;
    const int yg  = tid >> 4;

    // Gaussian taps (matches np float32: exp(-(i-5)^2/4.5) / sum)
    float g[11];
    {
        float s = 0.f;
#pragma unroll
        for (int i = 0; i < 11; i++) {
            float d = (float)(i - 5);
            g[i] = expf(-d * d / 4.5f);
            s += g[i];
        }
#pragma unroll
        for (int i = 0; i < 11; i++) g[i] /= s;
    }

    const int nItems = P.blk0[5];

    for (;;) {
        if (tid == 0) sItem = (int)atomicAdd(&wsu[21], 1u);
        __syncthreads();
        const int item = sItem;
        if (item >= nItems) break;

        int level = 0;
#pragma unroll
        for (int l = 1; l < 5; l++)
            if (item >= P.blk0[l]) level = l;
        int rel = item - P.blk0[level];
        const int D   = P.D[level];
        const int O   = P.O[level];
        const int ZC  = P.zc[level];
        const int nTx = P.nTx[level];
        const int nTy = P.nTy[level];

        const int tx = rel % nTx;  rel /= nTx;
        const int ty = rel % nTy;  rel /= nTy;
        const int batch = rel & 1;
        const int chunk = rel >> 1;

        const int oz0 = chunk * ZC;
        const int oz1 = min(oz0 + ZC, O);
        const int nplanes = oz1 - oz0 + 10;
        const int ox0 = tx * TSX;
        const int oy0 = ty * TSY;
        const int D2  = D * D;
        const float* A = P.A[level] + (long)batch * D * D2;
        const float* B = P.B[level] + (long)batch * D * D2;

        // C1/C2 from this level's img1 min/max (phase 1)
        float mxv = dec_f(wsu[15 + level]);
        float mnv = dec_f(wsu[10 + level]);
        float maxval = (mxv > 128.f) ? 255.f : 1.f;
        float minval = (mnv < -0.5f) ? -1.f : 0.f;
        float Lr = maxval - minval;
        float C1 = 0.01f * Lr; C1 *= C1;
        float C2 = 0.03f * Lr; C2 *= C2;

        // per-thread staging slots (plane-invariant offsets); 1092 = 42*26
        int  poff[5], sidx[5];
        bool pval[5];
#pragma unroll
        for (int k = 0; k < 5; k++) {
            int idx = tid + (k << 8);
            pval[k] = (idx < NPIX);
            int row = idx / EXC;
            int c   = idx - row * EXC;
            sidx[k] = row * SPS + c;
            int gyy = min(oy0 + row, D - 1);
            int gxx = min(ox0 + c,   D - 1);
            poff[k] = gyy * D + gxx;
        }

        float Acc[10][11] = {};
        float ssim_acc = 0.f, cs_acc = 0.f;

        const bool vx  = (ox0 + col < O);
        const bool vy0 = vx && (oy0 + 2 * yg < O);
        const bool vy1 = vx && (oy0 + 2 * yg + 1 < O);

        float2 Pld[5];
        {
            long zoff = (long)oz0 * D2;
#pragma unroll
            for (int k = 0; k < 5; k++)
                if (pval[k]) Pld[k] = make_float2(A[zoff + poff[k]], B[zoff + poff[k]]);
        }

        for (int pc = 0; pc < nplanes; ++pc) {
            __syncthreads();
#pragma unroll
            for (int k = 0; k < 5; k++)
                if (pval[k]) S[sidx[k]] = Pld[k];
            if (pc + 1 < nplanes) {
                long zoff = (long)(oz0 + pc + 1) * D2;
#pragma unroll
                for (int k = 0; k < 5; k++)
                    if (pval[k]) Pld[k] = make_float2(A[zoff + poff[k]], B[zoff + poff[k]]);
            }
            __syncthreads();

            // ---- x-conv: 168 tasks, each a run of 4 output cols in one ext row
            if (tid < EXR * 4) {
                int row = tid >> 2;
                int cg2 = tid & 3;
                const float4* srow = (const float4*)(S + row * SPS);
                float pa[14], pb[14];
#pragma unroll
                for (int i = 0; i < 7; i++) {
                    float4 q = srow[2 * cg2 + i];
                    pa[2 * i] = q.x; pb[2 * i] = q.y;
                    pa[2 * i + 1] = q.z; pb[2 * i + 1] = q.w;
                }
#pragma unroll
                for (int cc = 0; cc < 4; cc++) {
                    float m1 = 0.f, m2 = 0.f, aa = 0.f, bb = 0.f, ab = 0.f;
#pragma unroll
                    for (int j = 0; j < 11; j++) {
                        float w = g[j];
                        float a = pa[cc + j], b = pb[cc + j];
                        float wa = w * a, wb = w * b;
                        m1 += wa; m2 += wb;
                        aa += wa * a; bb += wb * b; ab += wa * b;
                    }
                    int o = row * TPS + 4 * cg2 + cc;
                    TX4[o] = make_float4(m1, m2, aa, bb);
                    TXe[o] = ab;
                }
            }
            __syncthreads();

            // ---- y-conv: 2 output rows share 12 row-reads
            float se[5] = {0.f, 0.f, 0.f, 0.f, 0.f};
            float so[5] = {0.f, 0.f, 0.f, 0.f, 0.f};
#pragma unroll
            for (int j = 0; j < 12; j++) {
                int o = (2 * yg + j) * TPS + col;
                float4 q = TX4[o];
                float e  = TXe[o];
                if (j < 11) {
                    float w = g[j];
                    se[0] += w * q.x; se[1] += w * q.y; se[2] += w * q.z;
                    se[3] += w * q.w; se[4] += w * e;
                }
                if (j > 0) {
                    float w = g[j - 1];
                    so[0] += w * q.x; so[1] += w * q.y; so[2] += w * q.z;
                    so[3] += w * q.w; so[4] += w * e;
                }
            }

            // ---- systolic z-accumulate
#pragma unroll
            for (int f = 0; f < 5; f++) {
#pragma unroll
                for (int k = 0; k < 10; k++)
                    Acc[2 * f][k] = fmaf(g[10 - k], se[f], Acc[2 * f][k + 1]);
                Acc[2 * f][10] = g[0] * se[f];
#pragma unroll
                for (int k = 0; k < 10; k++)
                    Acc[2 * f + 1][k] = fmaf(g[10 - k], so[f], Acc[2 * f + 1][k + 1]);
                Acc[2 * f + 1][10] = g[0] * so[f];
            }

            if (pc >= 10) {
#pragma unroll
                for (int rr = 0; rr < 2; rr++) {
                    bool valid = rr ? vy1 : vy0;
                    if (!valid) continue;
                    float m1  = Acc[0 + rr][0], m2  = Acc[2 + rr][0];
                    float s11 = Acc[4 + rr][0], s22 = Acc[6 + rr][0], s12 = Acc[8 + rr][0];
                    float mu11 = m1 * m1, mu22 = m2 * m2, mu12 = m1 * m2;
                    float sg1 = s11 - mu11, sg2 = s22 - mu22, sg12 = s12 - mu12;
                    float v1 = 2.f * sg12 + C2;
                    float v2 = sg1 + sg2 + C2;
                    cs_acc   += v1 / v2;
                    ssim_acc += ((2.f * mu12 + C1) * v1) / ((mu11 + mu22 + C1) * v2);
                }
            }
        }

        // block reduce + one atomic pair; last finished item computes output
        RED[tid] = make_float2(ssim_acc, cs_acc);
        __syncthreads();
        for (int s = 128; s > 0; s >>= 1) {
            if (tid < s) {
                RED[tid].x += RED[tid + s].x;
                RED[tid].y += RED[tid + s].y;
            }
            __syncthreads();
        }
        if (tid == 0) {
            atomicAdd(&wsf[level],     RED[0].x);
            atomicAdd(&wsf[5 + level], RED[0].y);
            __threadfence();
            unsigned prev = atomicAdd(&wsu[20], 1u);
            if (prev == (unsigned)(nItems - 1)) {
                double w[5];
                w[0] = (double)0.0448f; w[1] = (double)0.2856f; w[2] = (double)0.3001f;
                w[3] = (double)0.2363f; w[4] = (double)0.1333f;
                double prod = 1.0;
                for (int l = 0; l < 4; l++) {
                    float cs = atomicAdd(&wsf[5 + l], 0.0f);
                    prod *= pow((double)cs / P.cnt[l], w[l]);
                }
                float sm = atomicAdd(&wsf[4], 0.0f);
                prod *= pow((double)sm / P.cnt[4], w[4]);
                P.out[0] = (float)prod;
            }
        }
    }
}

extern "C" void kernel_launch(void* const* d_in, const int* in_sizes, int n_in,
                              void* d_out, int out_size, void* d_ws, size_t ws_size,
                              hipStream_t stream) {
    (void)in_sizes; (void)n_in; (void)out_size; (void)ws_size;
    const float* img1 = (const float*)d_in[0];
    const float* img2 = (const float*)d_in[1];
    float* wsf = (float*)d_ws;
    float* out = (float*)d_out;

    const int Ds[5]  = {192, 96, 48, 24, 12};
    const int ZCs[5] = {26, 16, 14, 14, 2};

    // pyramid buffers in workspace
    float* bufA[5] = {nullptr};
    float* bufB[5] = {nullptr};
    size_t o = 32;
    for (int l = 1; l < 5; l++) {
        long n = 2L * Ds[l] * Ds[l] * Ds[l];
        bufA[l] = wsf + o; o += (size_t)n;
        bufB[l] = wsf + o; o += (size_t)n;
    }

    MegaParams P;
    P.src[0] = img1; P.src[1] = img2;
    for (int l = 1; l < 5; l++) { P.dst[0][l - 1] = bufA[l]; P.dst[1][l - 1] = bufB[l]; }
    P.A[0] = img1; P.B[0] = img2;
    for (int l = 1; l < 5; l++) { P.A[l] = bufA[l]; P.B[l] = bufB[l]; }
    P.out = out;
    int acc = 0;
    for (int l = 0; l < 5; l++) {
        int D = Ds[l], O = D - 10, ZC = ZCs[l];
        int nTx = (O + TSX - 1) / TSX;
        int nTy = (O + TSY - 1) / TSY;
        int ZCn = (O + ZC - 1) / ZC;
        P.D[l] = D; P.O[l] = O; P.zc[l] = ZC; P.nTx[l] = nTx; P.nTy[l] = nTy;
        P.blk0[l] = acc;
        acc += nTx * nTy * 2 * ZCn;
        double Od = (double)O;
        P.cnt[l] = 2.0 * Od * Od * Od;
    }
    P.blk0[5] = acc;

    // cooperative grid: co-resident capacity (gfx950: 256 CUs), capped at 512
    int nb = 0;
    hipOccupancyMaxActiveBlocksPerMultiprocessor(&nb, mega_kernel, 256, 0);
    if (nb < 1) nb = 1;
    int G = nb * 256;
    if (G > 512) G = 512;

    void* args[] = {(void*)&P, (void*)&wsf};
    hipLaunchCooperativeKernel((const void*)mega_kernel, dim3(G), dim3(256),
                               args, 0, stream);
}

// Round 7
// 377.203 us; speedup vs baseline: 1.4221x; 1.4221x over previous
//
#include <hip/hip_runtime.h>
#include <math.h>

// ---------------------------------------------------------------------------
// MS-SSIM 3D (window 11, sigma 1.5, 5 levels) for (2,1,192,192,192) fp32 pairs.
//
// ws float layout:
//   [0..4]   ssim_sum[level]      (float atomics)
//   [5..9]   cs_sum[level]        (float atomics)
//   [10..14] min_enc[level]       (sortable-uint atomicMin)
//   [15..19] max_enc[level]       (sortable-uint atomicMax)
//   [20]     done counter (uint)
//   [32.. ]  pyramid images (levels 1..4, img1 then img2 per level)
//
// R7: revert R6's persistent-block mega-kernel (1.6x/plane regression:
// serialized item boundaries + regalloc spills). R5 ssim kept byte-identical.
// Pyramid rewritten for bandwidth: 1728 blocks, float4 loads, 16 loads in
// flight per thread before compute (was 8B loads, 864 blocks, latency-bound).
// ---------------------------------------------------------------------------

__device__ __forceinline__ unsigned enc_f(float f) {
    unsigned u = __float_as_uint(f);
    return (u & 0x80000000u) ? ~u : (u | 0x80000000u);
}
__device__ __forceinline__ float dec_f(unsigned e) {
    unsigned u = (e & 0x80000000u) ? (e ^ 0x80000000u) : ~e;
    return __uint_as_float(u);
}

__global__ void init_kernel(float* wsf) {
    unsigned* wsu = (unsigned*)wsf;
    int t = threadIdx.x;
    if (t < 10)       wsf[t] = 0.0f;
    else if (t < 15)  wsu[t] = 0xFFFFFFFFu;  // min slots
    else if (t < 20)  wsu[t] = 0u;           // max slots
    else if (t == 20) wsu[t] = 0u;           // done counter
}

// ---------------------------------------------------------------------------
// Fused pyramid, BW-optimized. Block owns a 32x32x16 (x,y,z) region of L0 for
// one (img,batch): 16x16x8 of L1 via float4 loads (16 in flight per thread),
// then 8x8x4 L2, 4x4x2 L3, 2x2x1 L4 through LDS. Per-level min/max of img1
// block-reduced, one atomic pair per level per img1 block.
// Grid: 432 regions * 2 batches * 2 images = 1728 blocks (6.75/CU).
// ---------------------------------------------------------------------------
struct PyrParams {
    const float* src[2];   // img1, img2
    float* dst[2][4];      // [img][level-1]
};

__launch_bounds__(256, 4)
__global__ void pyramid_kernel(PyrParams P, float* wsf) {
    __shared__ __align__(16) float L1[8 * 256];  // 8 z * (16y*16x)
    __shared__ float L2s[256];                   // 4*8*8
    __shared__ float L3s[32];                    // 2*4*4
    __shared__ float smn[4], smx[4];
    unsigned* wsu = (unsigned*)wsf;

    const int tid = threadIdx.x;
    int blk = blockIdx.x;
    int r = blk % 432; blk /= 432;
    const int batch = blk & 1;
    const int im = blk >> 1;
    const int rx = r % 6, ry = (r / 6) % 6, rz = r / 36;   // rz 0..11

    const long N0 = 192L * 192 * 192;
    const float* src = P.src[im] + (long)batch * N0;
    float* d1 = P.dst[im][0] + (long)batch * 96 * 96 * 96;
    float* d2 = P.dst[im][1] + (long)batch * 48 * 48 * 48;
    float* d3 = P.dst[im][2] + (long)batch * 24 * 24 * 24;
    float* d4 = P.dst[im][3] + (long)batch * 12 * 12 * 12;

    const int tx = tid & 7;          // float4 x-group -> 2 L1 outputs
    const int ty = (tid >> 3) & 15;  // L1 y row
    const int tz = tid >> 7;         // 0..1, each handles 4 L1 z planes

    float mnv[5], mxv[5];
#pragma unroll
    for (int l = 0; l < 5; l++) { mnv[l] = INFINITY; mxv[l] = -INFINITY; }

    const long D = 192, D2 = 192L * 192;
    const int gx = rx * 32 + 4 * tx;
    const int gy = ry * 32 + 2 * ty;

    // ---- batch all 16 float4 loads (full MLP), then compute
    float4 v[4][4];
#pragma unroll
    for (int i = 0; i < 4; i++) {
        const int gz = rz * 16 + 2 * (tz * 4 + i);
        long base = (long)gz * D2 + (long)gy * D + gx;
        v[i][0] = *(const float4*)(src + base);
        v[i][1] = *(const float4*)(src + base + D);
        v[i][2] = *(const float4*)(src + base + D2);
        v[i][3] = *(const float4*)(src + base + D2 + D);
    }
#pragma unroll
    for (int i = 0; i < 4; i++) {
        float lo = INFINITY, hi = -INFINITY;
        float se = 0.f, so = 0.f;
#pragma unroll
        for (int k = 0; k < 4; k++) {
            float4 q = v[i][k];
            lo = fminf(lo, fminf(fminf(q.x, q.y), fminf(q.z, q.w)));
            hi = fmaxf(hi, fmaxf(fmaxf(q.x, q.y), fmaxf(q.z, q.w)));
            se += q.x + q.y;
            so += q.z + q.w;
        }
        mnv[0] = fminf(mnv[0], lo); mxv[0] = fmaxf(mxv[0], hi);
        float o0 = se * 0.125f, o1 = so * 0.125f;
        mnv[1] = fminf(mnv[1], fminf(o0, o1));
        mxv[1] = fmaxf(mxv[1], fmaxf(o0, o1));
        const int z1 = tz * 4 + i;
        *(float2*)(d1 + (long)(rz * 8 + z1) * 96 * 96 + (ry * 16 + ty) * 96
                   + (rx * 16 + 2 * tx)) = make_float2(o0, o1);
        *(float2*)&L1[z1 * 256 + ty * 16 + 2 * tx] = make_float2(o0, o1);
    }
    __syncthreads();

    // ---- L2: 8x8x4 region outputs, 1/thread
    {
        int x = tid & 7, y = (tid >> 3) & 7, z = tid >> 6;   // z 0..3
        float s = (L1[(2 * z) * 256 + (2 * y) * 16 + 2 * x] +
                   L1[(2 * z) * 256 + (2 * y) * 16 + 2 * x + 1] +
                   L1[(2 * z) * 256 + (2 * y + 1) * 16 + 2 * x] +
                   L1[(2 * z) * 256 + (2 * y + 1) * 16 + 2 * x + 1] +
                   L1[(2 * z + 1) * 256 + (2 * y) * 16 + 2 * x] +
                   L1[(2 * z + 1) * 256 + (2 * y) * 16 + 2 * x + 1] +
                   L1[(2 * z + 1) * 256 + (2 * y + 1) * 16 + 2 * x] +
                   L1[(2 * z + 1) * 256 + (2 * y + 1) * 16 + 2 * x + 1]) * 0.125f;
        mnv[2] = fminf(mnv[2], s); mxv[2] = fmaxf(mxv[2], s);
        d2[(long)(rz * 4 + z) * 48 * 48 + (ry * 8 + y) * 48 + (rx * 8 + x)] = s;
        L2s[z * 64 + y * 8 + x] = s;
    }
    __syncthreads();

    // ---- L3: 4x4x2 region outputs
    if (tid < 32) {
        int x = tid & 3, y = (tid >> 2) & 3, z = tid >> 4;   // z 0..1
        float s = (L2s[(2 * z) * 64 + (2 * y) * 8 + 2 * x] +
                   L2s[(2 * z) * 64 + (2 * y) * 8 + 2 * x + 1] +
                   L2s[(2 * z) * 64 + (2 * y + 1) * 8 + 2 * x] +
                   L2s[(2 * z) * 64 + (2 * y + 1) * 8 + 2 * x + 1] +
                   L2s[(2 * z + 1) * 64 + (2 * y) * 8 + 2 * x] +
                   L2s[(2 * z + 1) * 64 + (2 * y) * 8 + 2 * x + 1] +
                   L2s[(2 * z + 1) * 64 + (2 * y + 1) * 8 + 2 * x] +
                   L2s[(2 * z + 1) * 64 + (2 * y + 1) * 8 + 2 * x + 1]) * 0.125f;
        mnv[3] = fminf(mnv[3], s); mxv[3] = fmaxf(mxv[3], s);
        d3[(long)(rz * 2 + z) * 24 * 24 + (ry * 4 + y) * 24 + (rx * 4 + x)] = s;
        L3s[z * 16 + y * 4 + x] = s;
    }
    __syncthreads();

    // ---- L4: 2x2x1 region outputs
    if (tid < 4) {
        int x = tid & 1, y = tid >> 1;
        float s = (L3s[(2 * y) * 4 + 2 * x]       + L3s[(2 * y) * 4 + 2 * x + 1] +
                   L3s[(2 * y + 1) * 4 + 2 * x]   + L3s[(2 * y + 1) * 4 + 2 * x + 1] +
                   L3s[16 + (2 * y) * 4 + 2 * x]  + L3s[16 + (2 * y) * 4 + 2 * x + 1] +
                   L3s[16 + (2 * y + 1) * 4 + 2 * x] +
                   L3s[16 + (2 * y + 1) * 4 + 2 * x + 1]) * 0.125f;
        mnv[4] = fminf(mnv[4], s); mxv[4] = fmaxf(mxv[4], s);
        d4[(long)rz * 144 + (ry * 2 + y) * 12 + (rx * 2 + x)] = s;
    }

    // ---- per-level block min/max reduce; atomics only from img1 blocks
    const int lane = tid & 63, w = tid >> 6;
#pragma unroll
    for (int l = 0; l < 5; l++) {
        float mn = mnv[l], mx = mxv[l];
        for (int o = 32; o; o >>= 1) {
            mn = fminf(mn, __shfl_down(mn, o));
            mx = fmaxf(mx, __shfl_down(mx, o));
        }
        __syncthreads();
        if (lane == 0) { smn[w] = mn; smx[w] = mx; }
        __syncthreads();
        if (tid == 0 && im == 0) {
            for (int i = 1; i < 4; i++) { mn = fminf(mn, smn[i]); mx = fmaxf(mx, smx[i]); }
            atomicMin(&wsu[10 + l], enc_f(mn));
            atomicMax(&wsu[15 + l], enc_f(mx));
        }
    }
}

// ---------------------------------------------------------------------------
// Combined SSIM kernel (byte-identical to R5): one dispatch, all 5 levels +
// fused final reduction. 16(x) x 32(y) output tile; thread owns (col, 2 rows).
// ---------------------------------------------------------------------------
#define TSX 16
#define TSY 32
#define EXR 42            // ext rows (32+10)
#define EXC 26            // ext cols (16+10)
#define SPS 30            // S row stride in float2 (60 floats: odd float4 stride)
#define NPIX (EXR * EXC)  // 1092
#define TPS 17            // TX row stride (float4 / float units)

struct AllParams {
    const float* A[5];
    const float* B[5];
    int D[5], O[5], zc[5], nTx[5], nTy[5];
    int blk0[6];          // cumulative block offsets, level order 0..4
    float* out;
    double cnt[5];
};

__launch_bounds__(256, 2)
__attribute__((amdgpu_waves_per_eu(2, 2)))
__global__ void ssim_all_kernel(AllParams P, float* wsf) {
    __shared__ __align__(16) float2 S[EXR * SPS];    // 10080 B
    __shared__ __align__(16) float4 TX4[EXR * TPS];  // 11424 B
    __shared__ float TXe[EXR * TPS];                 //  2856 B
    __shared__ float2 RED[256];                      //  2048 B

    const int tid = threadIdx.x;
    const int col = tid & 15;
    const int yg  = tid >> 4;      // 0..15, owns output rows 2yg, 2yg+1

    // ---- decode level + tile from flat blockIdx.x
    int level = 0;
    {
        int b = blockIdx.x;
#pragma unroll
        for (int l = 1; l < 5; l++)
            if (b >= P.blk0[l]) level = l;
    }
    int rel = blockIdx.x - P.blk0[level];
    const int D   = P.D[level];
    const int O   = P.O[level];
    const int ZC  = P.zc[level];
    const int nTx = P.nTx[level];
    const int nTy = P.nTy[level];

    const int tx = rel % nTx;  rel /= nTx;
    const int ty = rel % nTy;  rel /= nTy;
    const int batch = rel & 1;
    const int chunk = rel >> 1;

    const int oz0 = chunk * ZC;
    const int oz1 = min(oz0 + ZC, O);
    const int nplanes = oz1 - oz0 + 10;
    const int ox0 = tx * TSX;
    const int oy0 = ty * TSY;
    const int D2  = D * D;
    const float* A = P.A[level] + (long)batch * D * D2;
    const float* B = P.B[level] + (long)batch * D * D2;

    // Gaussian taps (matches np float32: exp(-(i-5)^2/4.5) / sum)
    float g[11];
    {
        float s = 0.f;
#pragma unroll
        for (int i = 0; i < 11; i++) {
            float d = (float)(i - 5);
            g[i] = expf(-d * d / 4.5f);
            s += g[i];
        }
#pragma unroll
        for (int i = 0; i < 11; i++) g[i] /= s;
    }

    // C1/C2 from this level's img1 min/max (computed by pyramid kernel)
    const unsigned* wsu = (const unsigned*)wsf;
    float mxv = dec_f(wsu[15 + level]);
    float mnv = dec_f(wsu[10 + level]);
    float maxval = (mxv > 128.f) ? 255.f : 1.f;
    float minval = (mnv < -0.5f) ? -1.f : 0.f;
    float Lr = maxval - minval;
    float C1 = 0.01f * Lr; C1 *= C1;
    float C2 = 0.03f * Lr; C2 *= C2;

    // per-thread staging slots (plane-invariant offsets); 1092 = 42*26
    int  poff[5], sidx[5];
    bool pval[5];
#pragma unroll
    for (int k = 0; k < 5; k++) {
        int idx = tid + (k << 8);
        pval[k] = (idx < NPIX);
        int row = idx / EXC;
        int c   = idx - row * EXC;
        sidx[k] = row * SPS + c;
        int gy = min(oy0 + row, D - 1);
        int gx = min(ox0 + c,   D - 1);
        poff[k] = gy * D + gx;
    }

    // systolic z accumulators: Acc[f*2+r][k]; out plane completes in [..][0]
    float Acc[10][11] = {};
    float ssim_acc = 0.f, cs_acc = 0.f;

    const bool vx  = (ox0 + col < O);
    const bool vy0 = vx && (oy0 + 2 * yg < O);
    const bool vy1 = vx && (oy0 + 2 * yg + 1 < O);

    // preload first plane
    float2 Pld[5];
    {
        long zoff = (long)oz0 * D2;
#pragma unroll
        for (int k = 0; k < 5; k++)
            if (pval[k]) Pld[k] = make_float2(A[zoff + poff[k]], B[zoff + poff[k]]);
    }

    for (int pc = 0; pc < nplanes; ++pc) {
        __syncthreads();  // prior x-conv S-reads & y-conv TX-reads complete
#pragma unroll
        for (int k = 0; k < 5; k++)
            if (pval[k]) S[sidx[k]] = Pld[k];
        if (pc + 1 < nplanes) {
            long zoff = (long)(oz0 + pc + 1) * D2;
#pragma unroll
            for (int k = 0; k < 5; k++)
                if (pval[k]) Pld[k] = make_float2(A[zoff + poff[k]], B[zoff + poff[k]]);
        }
        __syncthreads();

        // ---- x-conv: 168 tasks, each a run of 4 output cols in one ext row
        if (tid < EXR * 4) {
            int row = tid >> 2;
            int cg  = tid & 3;          // c0 = 4*cg
            const float4* srow = (const float4*)(S + row * SPS);
            float pa[14], pb[14];
#pragma unroll
            for (int i = 0; i < 7; i++) {
                float4 q = srow[2 * cg + i];
                pa[2 * i] = q.x; pb[2 * i] = q.y;
                pa[2 * i + 1] = q.z; pb[2 * i + 1] = q.w;
            }
#pragma unroll
            for (int cc = 0; cc < 4; cc++) {
                float m1 = 0.f, m2 = 0.f, aa = 0.f, bb = 0.f, ab = 0.f;
#pragma unroll
                for (int j = 0; j < 11; j++) {
                    float w = g[j];
                    float a = pa[cc + j], b = pb[cc + j];
                    float wa = w * a, wb = w * b;
                    m1 += wa; m2 += wb;
                    aa += wa * a; bb += wb * b; ab += wa * b;
                }
                int o = row * TPS + 4 * cg + cc;
                TX4[o] = make_float4(m1, m2, aa, bb);
                TXe[o] = ab;
            }
        }
        __syncthreads();

        // ---- y-conv: 2 output rows share 12 row-reads
        float se[5] = {0.f, 0.f, 0.f, 0.f, 0.f};
        float so[5] = {0.f, 0.f, 0.f, 0.f, 0.f};
#pragma unroll
        for (int j = 0; j < 12; j++) {
            int o = (2 * yg + j) * TPS + col;
            float4 q = TX4[o];
            float e  = TXe[o];
            if (j < 11) {
                float w = g[j];
                se[0] += w * q.x; se[1] += w * q.y; se[2] += w * q.z;
                se[3] += w * q.w; se[4] += w * e;
            }
            if (j > 0) {
                float w = g[j - 1];
                so[0] += w * q.x; so[1] += w * q.y; so[2] += w * q.z;
                so[3] += w * q.w; so[4] += w * e;
            }
        }

        // ---- systolic z-accumulate: A[k] = g[10-k]*s + A[k+1]
#pragma unroll
        for (int f = 0; f < 5; f++) {
#pragma unroll
            for (int k = 0; k < 10; k++)
                Acc[2 * f][k] = fmaf(g[10 - k], se[f], Acc[2 * f][k + 1]);
            Acc[2 * f][10] = g[0] * se[f];
#pragma unroll
            for (int k = 0; k < 10; k++)
                Acc[2 * f + 1][k] = fmaf(g[10 - k], so[f], Acc[2 * f + 1][k + 1]);
            Acc[2 * f + 1][10] = g[0] * so[f];
        }

        // ---- completed output plane
        if (pc >= 10) {
#pragma unroll
            for (int r = 0; r < 2; r++) {
                bool valid = r ? vy1 : vy0;
                if (!valid) continue;
                float m1  = Acc[0 + r][0], m2  = Acc[2 + r][0];
                float s11 = Acc[4 + r][0], s22 = Acc[6 + r][0], s12 = Acc[8 + r][0];
                float mu11 = m1 * m1, mu22 = m2 * m2, mu12 = m1 * m2;
                float sg1 = s11 - mu11, sg2 = s22 - mu22, sg12 = s12 - mu12;
                float v1 = 2.f * sg12 + C2;
                float v2 = sg1 + sg2 + C2;
                cs_acc   += v1 / v2;
                ssim_acc += ((2.f * mu12 + C1) * v1) / ((mu11 + mu22 + C1) * v2);
            }
        }
    }

    // block reduce + one atomic pair; last block computes the final output
    RED[tid] = make_float2(ssim_acc, cs_acc);
    __syncthreads();
    for (int s = 128; s > 0; s >>= 1) {
        if (tid < s) {
            RED[tid].x += RED[tid + s].x;
            RED[tid].y += RED[tid + s].y;
        }
        __syncthreads();
    }
    if (tid == 0) {
        atomicAdd(&wsf[level],     RED[0].x);
        atomicAdd(&wsf[5 + level], RED[0].y);
        __threadfence();
        unsigned prev = atomicAdd((unsigned*)wsf + 20, 1u);
        if (prev == (unsigned)(P.blk0[5] - 1)) {
            double w[5];
            w[0] = (double)0.0448f; w[1] = (double)0.2856f; w[2] = (double)0.3001f;
            w[3] = (double)0.2363f; w[4] = (double)0.1333f;
            double prod = 1.0;
            for (int l = 0; l < 4; l++) {
                float cs = atomicAdd(&wsf[5 + l], 0.0f);
                prod *= pow((double)cs / P.cnt[l], w[l]);
            }
            float sm = atomicAdd(&wsf[4], 0.0f);
            prod *= pow((double)sm / P.cnt[4], w[4]);
            P.out[0] = (float)prod;
        }
    }
}

extern "C" void kernel_launch(void* const* d_in, const int* in_sizes, int n_in,
                              void* d_out, int out_size, void* d_ws, size_t ws_size,
                              hipStream_t stream) {
    (void)in_sizes; (void)n_in; (void)out_size; (void)ws_size;
    const float* img1 = (const float*)d_in[0];
    const float* img2 = (const float*)d_in[1];
    float* wsf = (float*)d_ws;
    float* out = (float*)d_out;

    const int Ds[5]  = {192, 96, 48, 24, 12};
    const int ZCs[5] = {26, 16, 14, 14, 2};

    // pyramid buffers in workspace
    float* bufA[5] = {nullptr};
    float* bufB[5] = {nullptr};
    size_t o = 32;
    for (int l = 1; l < 5; l++) {
        long n = 2L * Ds[l] * Ds[l] * Ds[l];
        bufA[l] = wsf + o; o += (size_t)n;
        bufB[l] = wsf + o; o += (size_t)n;
    }

    init_kernel<<<1, 64, 0, stream>>>(wsf);

    PyrParams PP;
    PP.src[0] = img1; PP.src[1] = img2;
    for (int l = 1; l < 5; l++) { PP.dst[0][l - 1] = bufA[l]; PP.dst[1][l - 1] = bufB[l]; }
    pyramid_kernel<<<432 * 2 * 2, 256, 0, stream>>>(PP, wsf);

    AllParams P;
    P.A[0] = img1; P.B[0] = img2;
    for (int l = 1; l < 5; l++) { P.A[l] = bufA[l]; P.B[l] = bufB[l]; }
    P.out = out;
    int acc = 0;
    for (int l = 0; l < 5; l++) {
        int D = Ds[l], O = D - 10, ZC = ZCs[l];
        int nTx = (O + TSX - 1) / TSX;
        int nTy = (O + TSY - 1) / TSY;
        int ZCn = (O + ZC - 1) / ZC;
        P.D[l] = D; P.O[l] = O; P.zc[l] = ZC; P.nTx[l] = nTx; P.nTy[l] = nTy;
        P.blk0[l] = acc;
        acc += nTx * nTy * 2 * ZCn;
        double Od = (double)O;
        P.cnt[l] = 2.0 * Od * Od * Od;
    }
    P.blk0[5] = acc;
    ssim_all_kernel<<<acc, 256, 0, stream>>>(P, wsf);
}